// Round 9
// baseline (157.509 us; speedup 1.0000x reference)
//
#include <hip/hip_runtime.h>
#include <math.h>

#define TB 16
#define TL 8192
#define TC 64

constexpr float INV_BL = 1.0f / (16.0f * 8192.0f);
constexpr float EPSV = 1e-5f;
constexpr float INV_SQRT_H = 0.17677669529663687f; // 1/sqrt(32)

// workspace offsets (floats) — ws is 256 MiB, no overlays needed
#define WS_G      0        /* [16][64][64] */
#define WS_SX     65536    /* [16][64] */
#define WS_STATS  66560    /* s1[64] d1[64] s2[64] d2[64] */
#define WS_M      66816    /* [16][64][64] */
#define WS_N      132352   /* [16][64][64] */
#define WS_S1T    197888   /* [16][64][256] -> ends 460032 */
#define WS_PT     460032   /* attn^T [16][256][256] -> ends 1508608 */
#define WS_GPART  1508608  /* [16][32][4096] -> ends 3605760 */
#define WS_SXPART 3605760  /* [16][32][64] -> ends 3638528 */
#define WS_V1     3638528  /* [16][256][64] -> ends 3900672 */

typedef __attribute__((ext_vector_type(8))) short short8v;  // 8 bf16 (4 VGPRs)
typedef __attribute__((ext_vector_type(4))) float f32x4;    // MFMA C/D

__device__ __forceinline__ ushort bf16rne(float f){
  uint u = __float_as_uint(f);
  u += 0x7FFF + ((u >> 16) & 1);
  return (ushort)(u >> 16);
}

// granule-swizzled address (in ushorts): tile [64 ch][128 k] bf16, granule = 8 bf16
__device__ __forceinline__ int fraddr(int ch, int g){
  return ch*128 + 8*(g ^ (ch & 7));
}

// ---------------- K1: Gram partials + row sums (v6: MFMA, 32 chunks, 2 blocks/CU) ----------------
// grid (32 chunk, 16 b), 512 threads. Subtile 64ch x 128l, 2 subtiles, double-buffered.
__global__ __launch_bounds__(512) void k1_gram(const float* __restrict__ x,
                                               float* __restrict__ ws){
  __shared__ ushort Xh[2][64*128];
  __shared__ ushort Xl[2][64*128];
  const int b = blockIdx.y, chunk = blockIdx.x;
  const int t = threadIdx.x;
  const int lane = t & 63;
  const int w = __builtin_amdgcn_readfirstlane(t >> 6);
  const int ti  = w >> 1;
  const int tj0 = (w & 1) * 2;
  const int ch0 = t >> 4, oct0 = t & 15;
  const int ch1 = ch0 + 32;
  const float* xb = x + (size_t)b*TC*TL + (size_t)chunk*256;
  f32x4 acc0 = {0.f,0.f,0.f,0.f}, acc1 = {0.f,0.f,0.f,0.f};
  float sx0 = 0.f, sx1 = 0.f;
  const int wa0 = ch0*128 + 8*(oct0 ^ (ch0 & 7));
  const int wa1 = ch1*128 + 8*(oct0 ^ (ch1 & 7));
  // ---- prologue: stage subtile 0 into buf 0 ----
  {
    const float4 A0 = *(const float4*)(xb + ch0*TL + oct0*8);
    const float4 A1 = *(const float4*)(xb + ch0*TL + oct0*8 + 4);
    const float4 B0 = *(const float4*)(xb + ch1*TL + oct0*8);
    const float4 B1 = *(const float4*)(xb + ch1*TL + oct0*8 + 4);
    const float fa[8] = {A0.x,A0.y,A0.z,A0.w,A1.x,A1.y,A1.z,A1.w};
    const float fb[8] = {B0.x,B0.y,B0.z,B0.w,B1.x,B1.y,B1.z,B1.w};
    union { short8v v; ushort u[8]; } ha, la, hb, lb;
    #pragma unroll
    for (int i=0;i<8;++i){
      sx0 += fa[i]; sx1 += fb[i];
      const ushort h0 = bf16rne(fa[i]);
      ha.u[i] = h0;
      la.u[i] = bf16rne(fa[i] - __uint_as_float(((uint)h0)<<16));
      const ushort h1 = bf16rne(fb[i]);
      hb.u[i] = h1;
      lb.u[i] = bf16rne(fb[i] - __uint_as_float(((uint)h1)<<16));
    }
    *(short8v*)&Xh[0][wa0] = ha.v;
    *(short8v*)&Xl[0][wa0] = la.v;
    *(short8v*)&Xh[0][wa1] = hb.v;
    *(short8v*)&Xl[0][wa1] = lb.v;
  }
  __syncthreads();
  const int rA  = ti*16  + (lane & 15);
  const int rB0 = tj0*16 + (lane & 15);
  const int rB1 = rB0 + 16;
  const int gq  = lane >> 4;
  for (int s=0; s<2; ++s){
    const int cur = s & 1;
    float4 A0, A1, B0, B1;
    const bool pf = (s < 1);
    if (pf){
      A0 = *(const float4*)(xb + ch0*TL + 128 + oct0*8);
      A1 = *(const float4*)(xb + ch0*TL + 128 + oct0*8 + 4);
      B0 = *(const float4*)(xb + ch1*TL + 128 + oct0*8);
      B1 = *(const float4*)(xb + ch1*TL + 128 + oct0*8 + 4);
    }
    #pragma unroll
    for (int kk=0; kk<4; ++kk){
      const int g = kk*4 + gq;
      const short8v Ah  = *(const short8v*)&Xh[cur][fraddr(rA,  g)];
      const short8v Al  = *(const short8v*)&Xl[cur][fraddr(rA,  g)];
      const short8v Bh0 = *(const short8v*)&Xh[cur][fraddr(rB0, g)];
      const short8v Bl0 = *(const short8v*)&Xl[cur][fraddr(rB0, g)];
      const short8v Bh1 = *(const short8v*)&Xh[cur][fraddr(rB1, g)];
      const short8v Bl1 = *(const short8v*)&Xl[cur][fraddr(rB1, g)];
      acc0 = __builtin_amdgcn_mfma_f32_16x16x32_bf16(Ah, Bh0, acc0, 0, 0, 0);
      acc0 = __builtin_amdgcn_mfma_f32_16x16x32_bf16(Ah, Bl0, acc0, 0, 0, 0);
      acc0 = __builtin_amdgcn_mfma_f32_16x16x32_bf16(Al, Bh0, acc0, 0, 0, 0);
      acc0 = __builtin_amdgcn_mfma_f32_16x16x32_bf16(Al, Bl0, acc0, 0, 0, 0);
      acc1 = __builtin_amdgcn_mfma_f32_16x16x32_bf16(Ah, Bh1, acc1, 0, 0, 0);
      acc1 = __builtin_amdgcn_mfma_f32_16x16x32_bf16(Ah, Bl1, acc1, 0, 0, 0);
      acc1 = __builtin_amdgcn_mfma_f32_16x16x32_bf16(Al, Bh1, acc1, 0, 0, 0);
      acc1 = __builtin_amdgcn_mfma_f32_16x16x32_bf16(Al, Bl1, acc1, 0, 0, 0);
    }
    if (pf){
      const int nxt = cur ^ 1;
      const float fa[8] = {A0.x,A0.y,A0.z,A0.w,A1.x,A1.y,A1.z,A1.w};
      const float fb[8] = {B0.x,B0.y,B0.z,B0.w,B1.x,B1.y,B1.z,B1.w};
      union { short8v v; ushort u[8]; } ha, la, hb, lb;
      #pragma unroll
      for (int i=0;i<8;++i){
        sx0 += fa[i]; sx1 += fb[i];
        const ushort h0 = bf16rne(fa[i]);
        ha.u[i] = h0;
        la.u[i] = bf16rne(fa[i] - __uint_as_float(((uint)h0)<<16));
        const ushort h1 = bf16rne(fb[i]);
        hb.u[i] = h1;
        lb.u[i] = bf16rne(fb[i] - __uint_as_float(((uint)h1)<<16));
      }
      *(short8v*)&Xh[nxt][wa0] = ha.v;
      *(short8v*)&Xl[nxt][wa0] = la.v;
      *(short8v*)&Xh[nxt][wa1] = hb.v;
      *(short8v*)&Xl[nxt][wa1] = lb.v;
    }
    __syncthreads();
  }
  // C/D map: col=lane&15, row=(lane>>4)*4+r (m89/m91)
  float* Gp = ws + WS_GPART + (b*32 + chunk)*4096;
  const int col = lane & 15, rq = lane >> 4;
  #pragma unroll
  for (int r=0;r<4;++r){
    Gp[(ti*16 + rq*4 + r)*64 + tj0*16      + col] = acc0[r];
    Gp[(ti*16 + rq*4 + r)*64 + tj0*16 + 16 + col] = acc1[r];
  }
  #pragma unroll
  for (int off=1; off<16; off<<=1){
    sx0 += __shfl_xor(sx0, off, 16);
    sx1 += __shfl_xor(sx1, off, 16);
  }
  if (oct0 == 0){
    float* Sp = ws + WS_SXPART + (b*32+chunk)*64;
    Sp[ch0] = sx0;
    Sp[ch1] = sx1;
  }
}

// ---------------- KA: fused G/Sx reduce + S1^T columns ----------------
// grid (16 cq, 16 b): block reduces G cols [4cq,4cq+4) and computes those S1T cols.
__global__ __launch_bounds__(256) void kA(const float* __restrict__ wq,
                                          float* __restrict__ ws){
  __shared__ float gcol[64*5];
  __shared__ float wqL[256*17];
  const int b = blockIdx.y, cq = blockIdx.x;
  const int t = threadIdx.x;
  const int k = t>>2, cj = t&3;
  const int c = 4*cq + cj;
  {
    const float* Gp = ws + WS_GPART + b*32*4096 + k*64 + c;
    float s = 0.f;
    #pragma unroll 8
    for (int ch=0; ch<32; ++ch) s += Gp[ch*4096];
    ws[WS_G + b*4096 + k*64 + c] = s;
    gcol[k*5 + cj] = s;
  }
  if (cq==0){
    if (t<64){
      float sv = 0.f;
      #pragma unroll 8
      for (int ch=0; ch<32; ++ch) sv += ws[WS_SXPART + (b*32+ch)*64 + t];
      ws[WS_SX + b*64 + t] = sv;
    }
    if (b==0) ws[WS_STATS + t] = 0.f;
  }
  __syncthreads();
  float sc0=0.f, sc1=0.f, sc2=0.f, sc3=0.f;
  for (int ic=0; ic<4; ++ic){
    if (ic) __syncthreads();
    #pragma unroll
    for (int r=0;r<16;++r){
      const int e = t + 256*r;
      wqL[(e>>4)*17 + (e&15)] = wq[(e>>4)*64 + ic*16 + (e&15)];
    }
    __syncthreads();
    #pragma unroll
    for (int kk=0; kk<16; ++kk){
      const float wv = wqL[t*17 + kk];
      const int kg = ic*16 + kk;
      sc0 = fmaf(wv, gcol[kg*5+0], sc0);
      sc1 = fmaf(wv, gcol[kg*5+1], sc1);
      sc2 = fmaf(wv, gcol[kg*5+2], sc2);
      sc3 = fmaf(wv, gcol[kg*5+3], sc3);
    }
  }
  float* S1T = ws + WS_S1T + b*16384;
  S1T[(4*cq+0)*256 + t] = sc0;
  S1T[(4*cq+1)*256 + t] = sc1;
  S1T[(4*cq+2)*256 + t] = sc2;
  S1T[(4*cq+3)*256 + t] = sc3;
}

// ---------------- KB1: scores + column softmax -> P^T (global) ----------------
__global__ __launch_bounds__(256) void kb1_scores(const float* __restrict__ wk,
                                                  float* __restrict__ ws){
  __shared__ float scl[256*17];
  __shared__ float pstat[256];
  __shared__ float fstat[32];
  const int b = blockIdx.y, jp = blockIdx.x;
  const int j0 = jp*16;
  const int t = threadIdx.x;
  const float* S1Tb = ws + WS_S1T + b*16384;
  float sc[16];
  #pragma unroll
  for (int jj=0;jj<16;++jj) sc[jj]=0.f;
  #pragma unroll 2
  for (int k=0;k<64;++k){
    const float s1 = S1Tb[k*256 + t];
    const float* wkr = wk + j0*64 + k;
    #pragma unroll
    for (int jj=0;jj<16;++jj)
      sc[jj] = fmaf(wkr[jj*64], s1, sc[jj]);
  }
  #pragma unroll
  for (int jj=0;jj<16;++jj) scl[t*17+jj] = sc[jj];
  __syncthreads();
  const int col = t&15, ig = t>>4;
  {
    float m = -3.0e38f;
    #pragma unroll
    for (int q=0;q<16;++q) m = fmaxf(m, scl[(ig*16+q)*17 + col]);
    pstat[ig*16+col] = m;
  }
  __syncthreads();
  if (t<16){
    float m = -3.0e38f;
    #pragma unroll
    for (int q=0;q<16;++q) m = fmaxf(m, pstat[q*16+t]);
    fstat[t] = m;
  }
  __syncthreads();
  {
    const float mj = fstat[col];
    float s = 0.f;
    #pragma unroll
    for (int q=0;q<16;++q) s += __expf(scl[(ig*16+q)*17 + col] - mj);
    pstat[ig*16+col] = s;
  }
  __syncthreads();
  if (t<16){
    float s = 0.f;
    #pragma unroll
    for (int q=0;q<16;++q) s += pstat[q*16+t];
    fstat[16+t] = 1.f/s;
  }
  __syncthreads();
  float* PTb = ws + WS_PT + b*65536;
  #pragma unroll
  for (int jj=0;jj<16;++jj){
    const float p = __expf(sc[jj] - fstat[jj]) * fstat[16+jj];
    PTb[(j0+jj)*256 + t] = p;
  }
}

// ---------------- KB2: V1 = (P wv) * 1/sqrt(H) ----------------
__global__ __launch_bounds__(256) void kb2_v1(const float* __restrict__ wv,
                                              float* __restrict__ ws){
  __shared__ float PTl[64*65];
  const int b = blockIdx.y, iq = blockIdx.x;
  const int t = threadIdx.x;
  const int i = t&63;
  const int cg = __builtin_amdgcn_readfirstlane(t>>6);
  float acc[16];
  #pragma unroll
  for (int cc=0;cc<16;++cc) acc[cc]=0.f;
  const float* PTb = ws + WS_PT + b*65536 + iq*64;
  for (int jc=0;jc<4;++jc){
    __syncthreads();
    #pragma unroll
    for (int r=0;r<16;++r){
      const int e = t + 256*r;
      PTl[(e>>6)*65 + (e&63)] = PTb[(jc*64 + (e>>6))*256 + (e&63)];
    }
    __syncthreads();
    #pragma unroll 4
    for (int jj=0;jj<64;++jj){
      const float p = PTl[jj*65 + i];
      const float* wvr = wv + (jc*64+jj)*64 + cg*16;
      #pragma unroll
      for (int cc=0;cc<16;++cc)
        acc[cc] = fmaf(p, wvr[cc], acc[cc]);
    }
  }
  float* V1o = ws + WS_V1 + b*16384 + (iq*64+i)*64 + cg*16;
  #pragma unroll
  for (int cc=0;cc<16;++cc) V1o[cc] = acc[cc]*INV_SQRT_H;
}

// ---------------- KCD: M = wc @ V1 (full batch) + BN1 stats ----------------
// grid (16 b), 256 threads, 1 block/batch.
__global__ __launch_bounds__(256) void kcd(const float* __restrict__ wc,
                                           float* __restrict__ ws){
  __shared__ float V1l[256*64];   // 64 KB, linear
  __shared__ float wcs[64*65];    // i-chunk of wc
  __shared__ float Gl[64*67];
  __shared__ float Ml[64*65];
  __shared__ float Sxl[64];
  const int b = blockIdx.x, t = threadIdx.x;
  #pragma unroll 4
  for (int r=0;r<64;++r) V1l[t + 256*r] = ws[WS_V1 + b*16384 + t + 256*r];
  #pragma unroll 4
  for (int r=0;r<16;++r){
    const int e = t + 256*r;
    Gl[(e>>6)*67 + (e&63)] = ws[WS_G + b*4096 + e];
  }
  if (t<64) Sxl[t] = ws[WS_SX + b*64 + t];
  const int o = t>>2, cq4 = t&3;
  float acc[16];
  #pragma unroll
  for (int cc=0;cc<16;++cc) acc[cc]=0.f;
  for (int ic=0; ic<4; ++ic){
    __syncthreads();
    #pragma unroll
    for (int r=0;r<16;++r){
      const int e = t + 256*r;
      wcs[(e>>6)*65 + (e&63)] = wc[(e>>6)*256 + ic*64 + (e&63)];
    }
    __syncthreads();
    #pragma unroll 4
    for (int ii=0; ii<64; ++ii){
      const float wv = wcs[o*65 + ii];
      #pragma unroll
      for (int cc=0;cc<16;++cc)
        acc[cc] = fmaf(wv, V1l[(ic*64+ii)*64 + cq4*16 + cc], acc[cc]);
    }
  }
  #pragma unroll
  for (int cc=0;cc<16;++cc){
    Ml[o*65 + cq4*16 + cc] = acc[cc];
    ws[WS_M + b*4096 + o*64 + cq4*16 + cc] = acc[cc];
  }
  __syncthreads();
  const int q = t&15;
  #pragma unroll
  for (int ob=0; ob<4; ++ob){
    const int oo = ob*16 + (t>>4);
    float d = 0.f;
    #pragma unroll
    for (int kk=0;kk<4;++kk){
      const int k = q*4+kk;
      float s = 0.f;
      #pragma unroll 4
      for (int c=0;c<64;++c) s = fmaf(Gl[k*67+c], Ml[oo*65+c], s);
      d = fmaf(Ml[oo*65+k], s, d);
    }
    d += __shfl_xor(d, 1, 16);
    d += __shfl_xor(d, 2, 16);
    d += __shfl_xor(d, 4, 16);
    d += __shfl_xor(d, 8, 16);
    if (q==0){
      float s1 = 0.f;
      #pragma unroll 4
      for (int c=0;c<64;++c) s1 = fmaf(Ml[oo*65+c], Sxl[c], s1);
      atomicAdd(&ws[WS_STATS + oo], s1);
      atomicAdd(&ws[WS_STATS + 64 + oo], d);
    }
  }
}

// ---------------- KE: N = a1*(wl@M) + wl (full batch) + BN2 stats ----------------
// grid (16 b), 256 threads.
__global__ __launch_bounds__(256) void kE(const float* __restrict__ wl,
                                          const float* __restrict__ g1,
                                          float* __restrict__ ws){
  __shared__ float Ml[64*65];
  __shared__ float Gl[64*67];
  __shared__ float wls[64*65];
  __shared__ float Nl[64*65];
  __shared__ float Sxl[64], a1l[64];
  const int b = blockIdx.x, t = threadIdx.x;
  if (t<64){
    const float mean1 = ws[WS_STATS+t]*INV_BL;
    const float var1 = ws[WS_STATS+64+t]*INV_BL - mean1*mean1;
    a1l[t] = g1[t]*rsqrtf(var1 + EPSV);
    Sxl[t] = ws[WS_SX + b*64 + t];
  }
  #pragma unroll 4
  for (int r=0;r<16;++r){
    const int e = t + 256*r;
    Ml[(e>>6)*65 + (e&63)] = ws[WS_M + b*4096 + e];
    Gl[(e>>6)*67 + (e&63)] = ws[WS_G + b*4096 + e];
  }
  __syncthreads();
  #pragma unroll 4
  for (int r=0;r<16;++r){
    const int e = t + 256*r;
    wls[(e>>6)*65 + (e&63)] = wl[e] * a1l[e&63];
  }
  __syncthreads();
  const int o = t>>2, cq4 = t&3;
  {
    float acc[16];
    #pragma unroll
    for (int cc=0;cc<16;++cc) acc[cc]=0.f;
    #pragma unroll 4
    for (int k=0;k<64;++k){
      const float wv = wls[o*65 + k];
      #pragma unroll
      for (int cc=0;cc<16;++cc)
        acc[cc] = fmaf(wv, Ml[k*65 + cq4*16 + cc], acc[cc]);
    }
    #pragma unroll
    for (int cc=0;cc<16;++cc){
      const float nv = acc[cc] + wl[o*64 + cq4*16 + cc];
      Nl[o*65 + cq4*16 + cc] = nv;
      ws[WS_N + b*4096 + o*64 + cq4*16 + cc] = nv;
    }
  }
  __syncthreads();
  const int q = t&15;
  #pragma unroll
  for (int ob=0; ob<4; ++ob){
    const int oo = ob*16 + (t>>4);
    float d = 0.f;
    #pragma unroll
    for (int kk=0;kk<4;++kk){
      const int k = q*4+kk;
      float s = 0.f;
      #pragma unroll 4
      for (int c=0;c<64;++c) s = fmaf(Gl[k*67+c], Nl[oo*65+c], s);
      d = fmaf(Nl[oo*65+k], s, d);
    }
    d += __shfl_xor(d, 1, 16);
    d += __shfl_xor(d, 2, 16);
    d += __shfl_xor(d, 4, 16);
    d += __shfl_xor(d, 8, 16);
    if (q==0){
      float s2 = 0.f;
      #pragma unroll 4
      for (int c=0;c<64;++c) s2 = fmaf(Nl[oo*65+c], Sxl[c], s2);
      atomicAdd(&ws[WS_STATS + 128 + oo], s2);
      atomicAdd(&ws[WS_STATS + 192 + oo], d);
    }
  }
}

// ---------------- K3: out = relu(a2*(N x) + e) ----------------
__global__ __launch_bounds__(256) void k3_out(const float* __restrict__ x,
                                              const float* __restrict__ g2,
                                              const float* __restrict__ b2,
                                              const float* __restrict__ ws,
                                              float* __restrict__ out){
  __shared__ float a2l[64], el[64];
  const int b = blockIdx.y, lc = blockIdx.x;
  const int t = threadIdx.x;
  if (t<64){
    const float mu = ws[WS_STATS+128+t]*INV_BL;
    const float var2 = ws[WS_STATS+192+t]*INV_BL - mu*mu;
    const float a2 = g2[t]*rsqrtf(var2 + EPSV);
    a2l[t] = a2;
    el[t] = b2[t] - a2*mu;
  }
  __syncthreads();
  const int w = __builtin_amdgcn_readfirstlane(t >> 6);
  const int lane = t & 63;
  const int l = lc*256 + 4*lane;
  const float* Np = ws + WS_N + b*4096 + w*1024;
  const float* xb = x + b*TC*TL + l;
  float4 acc[16];
  #pragma unroll
  for (int oo=0;oo<16;++oo){ acc[oo].x=0.f; acc[oo].y=0.f; acc[oo].z=0.f; acc[oo].w=0.f; }
  #pragma unroll 4
  for (int c=0;c<64;++c){
    const float4 xv = *(const float4*)(xb + c*TL);
    #pragma unroll
    for (int oo=0;oo<16;++oo){
      const float nv = Np[oo*64 + c];
      acc[oo].x = fmaf(nv, xv.x, acc[oo].x);
      acc[oo].y = fmaf(nv, xv.y, acc[oo].y);
      acc[oo].z = fmaf(nv, xv.z, acc[oo].z);
      acc[oo].w = fmaf(nv, xv.w, acc[oo].w);
    }
  }
  #pragma unroll
  for (int oo=0;oo<16;++oo){
    const float a2v = a2l[w*16+oo], ev = el[w*16+oo];
    float4 r;
    r.x = fmaxf(fmaf(a2v, acc[oo].x, ev), 0.f);
    r.y = fmaxf(fmaf(a2v, acc[oo].y, ev), 0.f);
    r.z = fmaxf(fmaf(a2v, acc[oo].z, ev), 0.f);
    r.w = fmaxf(fmaf(a2v, acc[oo].w, ev), 0.f);
    *(float4*)(out + (b*TC + w*16 + oo)*TL + l) = r;
  }
}

extern "C" void kernel_launch(void* const* d_in, const int* in_sizes, int n_in,
                              void* d_out, int out_size, void* d_ws, size_t ws_size,
                              hipStream_t stream){
  const float* x  = (const float*)d_in[0];
  const float* wk = (const float*)d_in[1];
  const float* wq = (const float*)d_in[2];
  const float* wv = (const float*)d_in[3];
  const float* wc = (const float*)d_in[4];
  const float* g1 = (const float*)d_in[5];
  /* b1 (d_in[6]) provably cancels through BN2 mean-subtraction */
  const float* wl = (const float*)d_in[7];
  const float* g2 = (const float*)d_in[8];
  const float* b2 = (const float*)d_in[9];
  float* out = (float*)d_out;
  float* ws  = (float*)d_ws;

  k1_gram    <<<dim3(32,16), 512, 0, stream>>>(x, ws);
  kA         <<<dim3(16,16), 256, 0, stream>>>(wq, ws);
  kb1_scores <<<dim3(16,16), 256, 0, stream>>>(wk, ws);
  kb2_v1     <<<dim3(4,16),  256, 0, stream>>>(wv, ws);
  kcd        <<<16,          256, 0, stream>>>(wc, ws);
  kE         <<<16,          256, 0, stream>>>(wl, g1, ws);
  k3_out     <<<dim3(32,16), 256, 0, stream>>>(x, g2, b2, ws, out);
}

// Round 10
// 116.021 us; speedup vs baseline: 1.3576x; 1.3576x over previous
//
#include <hip/hip_runtime.h>
#include <math.h>

#define TB 16
#define TL 8192
#define TC 64

constexpr float INV_BL = 1.0f / (16.0f * 8192.0f);
constexpr float EPSV = 1e-5f;
constexpr float INV_SQRT_H = 0.17677669529663687f; // 1/sqrt(32)

// workspace offsets (floats) — ws is 256 MiB, no overlays
#define WS_G      0        /* [16][64][64] */
#define WS_SX     65536    /* [16][64] */
#define WS_STATS  66560    /* s1[64] d1[64] s2[64] d2[64] */
#define WS_M      66816    /* [16][64][64] */
#define WS_N      132352   /* [16][64][64] */
#define WS_S1T    197888   /* [16][64][256] -> ends 460032 */
#define WS_PT     460032   /* attn^T [16][256][256] -> ends 1508608 */
#define WS_GPART  1508608  /* [16][32][4096] -> ends 3605760 */
#define WS_SXPART 3605760  /* [16][32][64] -> ends 3638528 */
#define WS_V1     3638528  /* [16][256][64] -> ends 3900672 */
#define WS_MPART  3900672  /* [16][4][4096] -> ends 4162816 */

typedef __attribute__((ext_vector_type(8))) short short8v;  // 8 bf16 (4 VGPRs)
typedef __attribute__((ext_vector_type(4))) float f32x4;    // MFMA C/D

__device__ __forceinline__ ushort bf16rne(float f){
  uint u = __float_as_uint(f);
  u += 0x7FFF + ((u >> 16) & 1);
  return (ushort)(u >> 16);
}

// granule-swizzled address (in ushorts): tile [64 ch][128 k] bf16, granule = 8 bf16
__device__ __forceinline__ int fraddr(int ch, int g){
  return ch*128 + 8*(g ^ (ch & 7));
}

// ---------------- K1: Gram partials + row sums (v6: MFMA, 32 chunks, 2 blocks/CU) ----------------
__global__ __launch_bounds__(512) void k1_gram(const float* __restrict__ x,
                                               float* __restrict__ ws){
  __shared__ ushort Xh[2][64*128];
  __shared__ ushort Xl[2][64*128];
  const int b = blockIdx.y, chunk = blockIdx.x;
  const int t = threadIdx.x;
  const int lane = t & 63;
  const int w = __builtin_amdgcn_readfirstlane(t >> 6);
  const int ti  = w >> 1;
  const int tj0 = (w & 1) * 2;
  const int ch0 = t >> 4, oct0 = t & 15;
  const int ch1 = ch0 + 32;
  const float* xb = x + (size_t)b*TC*TL + (size_t)chunk*256;
  f32x4 acc0 = {0.f,0.f,0.f,0.f}, acc1 = {0.f,0.f,0.f,0.f};
  float sx0 = 0.f, sx1 = 0.f;
  const int wa0 = ch0*128 + 8*(oct0 ^ (ch0 & 7));
  const int wa1 = ch1*128 + 8*(oct0 ^ (ch1 & 7));
  {
    const float4 A0 = *(const float4*)(xb + ch0*TL + oct0*8);
    const float4 A1 = *(const float4*)(xb + ch0*TL + oct0*8 + 4);
    const float4 B0 = *(const float4*)(xb + ch1*TL + oct0*8);
    const float4 B1 = *(const float4*)(xb + ch1*TL + oct0*8 + 4);
    const float fa[8] = {A0.x,A0.y,A0.z,A0.w,A1.x,A1.y,A1.z,A1.w};
    const float fb[8] = {B0.x,B0.y,B0.z,B0.w,B1.x,B1.y,B1.z,B1.w};
    union { short8v v; ushort u[8]; } ha, la, hb, lb;
    #pragma unroll
    for (int i=0;i<8;++i){
      sx0 += fa[i]; sx1 += fb[i];
      const ushort h0 = bf16rne(fa[i]);
      ha.u[i] = h0;
      la.u[i] = bf16rne(fa[i] - __uint_as_float(((uint)h0)<<16));
      const ushort h1 = bf16rne(fb[i]);
      hb.u[i] = h1;
      lb.u[i] = bf16rne(fb[i] - __uint_as_float(((uint)h1)<<16));
    }
    *(short8v*)&Xh[0][wa0] = ha.v;
    *(short8v*)&Xl[0][wa0] = la.v;
    *(short8v*)&Xh[0][wa1] = hb.v;
    *(short8v*)&Xl[0][wa1] = lb.v;
  }
  __syncthreads();
  const int rA  = ti*16  + (lane & 15);
  const int rB0 = tj0*16 + (lane & 15);
  const int rB1 = rB0 + 16;
  const int gq  = lane >> 4;
  for (int s=0; s<2; ++s){
    const int cur = s & 1;
    float4 A0, A1, B0, B1;
    const bool pf = (s < 1);
    if (pf){
      A0 = *(const float4*)(xb + ch0*TL + 128 + oct0*8);
      A1 = *(const float4*)(xb + ch0*TL + 128 + oct0*8 + 4);
      B0 = *(const float4*)(xb + ch1*TL + 128 + oct0*8);
      B1 = *(const float4*)(xb + ch1*TL + 128 + oct0*8 + 4);
    }
    #pragma unroll
    for (int kk=0; kk<4; ++kk){
      const int g = kk*4 + gq;
      const short8v Ah  = *(const short8v*)&Xh[cur][fraddr(rA,  g)];
      const short8v Al  = *(const short8v*)&Xl[cur][fraddr(rA,  g)];
      const short8v Bh0 = *(const short8v*)&Xh[cur][fraddr(rB0, g)];
      const short8v Bl0 = *(const short8v*)&Xl[cur][fraddr(rB0, g)];
      const short8v Bh1 = *(const short8v*)&Xh[cur][fraddr(rB1, g)];
      const short8v Bl1 = *(const short8v*)&Xl[cur][fraddr(rB1, g)];
      acc0 = __builtin_amdgcn_mfma_f32_16x16x32_bf16(Ah, Bh0, acc0, 0, 0, 0);
      acc0 = __builtin_amdgcn_mfma_f32_16x16x32_bf16(Ah, Bl0, acc0, 0, 0, 0);
      acc0 = __builtin_amdgcn_mfma_f32_16x16x32_bf16(Al, Bh0, acc0, 0, 0, 0);
      acc0 = __builtin_amdgcn_mfma_f32_16x16x32_bf16(Al, Bl0, acc0, 0, 0, 0);
      acc1 = __builtin_amdgcn_mfma_f32_16x16x32_bf16(Ah, Bh1, acc1, 0, 0, 0);
      acc1 = __builtin_amdgcn_mfma_f32_16x16x32_bf16(Ah, Bl1, acc1, 0, 0, 0);
      acc1 = __builtin_amdgcn_mfma_f32_16x16x32_bf16(Al, Bh1, acc1, 0, 0, 0);
      acc1 = __builtin_amdgcn_mfma_f32_16x16x32_bf16(Al, Bl1, acc1, 0, 0, 0);
    }
    if (pf){
      const int nxt = cur ^ 1;
      const float fa[8] = {A0.x,A0.y,A0.z,A0.w,A1.x,A1.y,A1.z,A1.w};
      const float fb[8] = {B0.x,B0.y,B0.z,B0.w,B1.x,B1.y,B1.z,B1.w};
      union { short8v v; ushort u[8]; } ha, la, hb, lb;
      #pragma unroll
      for (int i=0;i<8;++i){
        sx0 += fa[i]; sx1 += fb[i];
        const ushort h0 = bf16rne(fa[i]);
        ha.u[i] = h0;
        la.u[i] = bf16rne(fa[i] - __uint_as_float(((uint)h0)<<16));
        const ushort h1 = bf16rne(fb[i]);
        hb.u[i] = h1;
        lb.u[i] = bf16rne(fb[i] - __uint_as_float(((uint)h1)<<16));
      }
      *(short8v*)&Xh[nxt][wa0] = ha.v;
      *(short8v*)&Xl[nxt][wa0] = la.v;
      *(short8v*)&Xh[nxt][wa1] = hb.v;
      *(short8v*)&Xl[nxt][wa1] = lb.v;
    }
    __syncthreads();
  }
  float* Gp = ws + WS_GPART + (b*32 + chunk)*4096;
  const int col = lane & 15, rq = lane >> 4;
  #pragma unroll
  for (int r=0;r<4;++r){
    Gp[(ti*16 + rq*4 + r)*64 + tj0*16      + col] = acc0[r];
    Gp[(ti*16 + rq*4 + r)*64 + tj0*16 + 16 + col] = acc1[r];
  }
  #pragma unroll
  for (int off=1; off<16; off<<=1){
    sx0 += __shfl_xor(sx0, off, 16);
    sx1 += __shfl_xor(sx1, off, 16);
  }
  if (oct0 == 0){
    float* Sp = ws + WS_SXPART + (b*32+chunk)*64;
    Sp[ch0] = sx0;
    Sp[ch1] = sx1;
  }
}

// ---------------- KA: fused G/Sx reduce + S1^T columns ----------------
__global__ __launch_bounds__(256) void kA(const float* __restrict__ wq,
                                          float* __restrict__ ws){
  __shared__ float gcol[64*5];
  __shared__ float wqL[256*17];
  const int b = blockIdx.y, cq = blockIdx.x;
  const int t = threadIdx.x;
  const int k = t>>2, cj = t&3;
  const int c = 4*cq + cj;
  {
    const float* Gp = ws + WS_GPART + b*32*4096 + k*64 + c;
    float s = 0.f;
    #pragma unroll 8
    for (int ch=0; ch<32; ++ch) s += Gp[ch*4096];
    ws[WS_G + b*4096 + k*64 + c] = s;
    gcol[k*5 + cj] = s;
  }
  if (cq==0){
    if (t<64){
      float sv = 0.f;
      #pragma unroll 8
      for (int ch=0; ch<32; ++ch) sv += ws[WS_SXPART + (b*32+ch)*64 + t];
      ws[WS_SX + b*64 + t] = sv;
    }
    if (b==0) ws[WS_STATS + t] = 0.f;
  }
  __syncthreads();
  float sc0=0.f, sc1=0.f, sc2=0.f, sc3=0.f;
  for (int ic=0; ic<4; ++ic){
    if (ic) __syncthreads();
    #pragma unroll
    for (int r=0;r<16;++r){
      const int e = t + 256*r;
      wqL[(e>>4)*17 + (e&15)] = wq[(e>>4)*64 + ic*16 + (e&15)];
    }
    __syncthreads();
    #pragma unroll
    for (int kk=0; kk<16; ++kk){
      const float wv = wqL[t*17 + kk];
      const int kg = ic*16 + kk;
      sc0 = fmaf(wv, gcol[kg*5+0], sc0);
      sc1 = fmaf(wv, gcol[kg*5+1], sc1);
      sc2 = fmaf(wv, gcol[kg*5+2], sc2);
      sc3 = fmaf(wv, gcol[kg*5+3], sc3);
    }
  }
  float* S1T = ws + WS_S1T + b*16384;
  S1T[(4*cq+0)*256 + t] = sc0;
  S1T[(4*cq+1)*256 + t] = sc1;
  S1T[(4*cq+2)*256 + t] = sc2;
  S1T[(4*cq+3)*256 + t] = sc3;
}

// ---------------- KB1: scores + column softmax -> P^T (global) ----------------
__global__ __launch_bounds__(256) void kb1_scores(const float* __restrict__ wk,
                                                  float* __restrict__ ws){
  __shared__ float scl[256*17];
  __shared__ float pstat[256];
  __shared__ float fstat[32];
  const int b = blockIdx.y, jp = blockIdx.x;
  const int j0 = jp*16;
  const int t = threadIdx.x;
  const float* S1Tb = ws + WS_S1T + b*16384;
  float sc[16];
  #pragma unroll
  for (int jj=0;jj<16;++jj) sc[jj]=0.f;
  #pragma unroll 2
  for (int k=0;k<64;++k){
    const float s1 = S1Tb[k*256 + t];
    const float* wkr = wk + j0*64 + k;
    #pragma unroll
    for (int jj=0;jj<16;++jj)
      sc[jj] = fmaf(wkr[jj*64], s1, sc[jj]);
  }
  #pragma unroll
  for (int jj=0;jj<16;++jj) scl[t*17+jj] = sc[jj];
  __syncthreads();
  const int col = t&15, ig = t>>4;
  {
    float m = -3.0e38f;
    #pragma unroll
    for (int q=0;q<16;++q) m = fmaxf(m, scl[(ig*16+q)*17 + col]);
    pstat[ig*16+col] = m;
  }
  __syncthreads();
  if (t<16){
    float m = -3.0e38f;
    #pragma unroll
    for (int q=0;q<16;++q) m = fmaxf(m, pstat[q*16+t]);
    fstat[t] = m;
  }
  __syncthreads();
  {
    const float mj = fstat[col];
    float s = 0.f;
    #pragma unroll
    for (int q=0;q<16;++q) s += __expf(scl[(ig*16+q)*17 + col] - mj);
    pstat[ig*16+col] = s;
  }
  __syncthreads();
  if (t<16){
    float s = 0.f;
    #pragma unroll
    for (int q=0;q<16;++q) s += pstat[q*16+t];
    fstat[16+t] = 1.f/s;
  }
  __syncthreads();
  float* PTb = ws + WS_PT + b*65536;
  #pragma unroll
  for (int jj=0;jj<16;++jj){
    const float p = __expf(sc[jj] - fstat[jj]) * fstat[16+jj];
    PTb[(j0+jj)*256 + t] = p;
  }
}

// ---------------- KB2: V1 = (P wv) * 1/sqrt(H) ----------------
__global__ __launch_bounds__(256) void kb2_v1(const float* __restrict__ wv,
                                              float* __restrict__ ws){
  __shared__ float PTl[64*65];
  const int b = blockIdx.y, iq = blockIdx.x;
  const int t = threadIdx.x;
  const int i = t&63;
  const int cg = __builtin_amdgcn_readfirstlane(t>>6);
  float acc[16];
  #pragma unroll
  for (int cc=0;cc<16;++cc) acc[cc]=0.f;
  const float* PTb = ws + WS_PT + b*65536 + iq*64;
  for (int jc=0;jc<4;++jc){
    __syncthreads();
    #pragma unroll
    for (int r=0;r<16;++r){
      const int e = t + 256*r;
      PTl[(e>>6)*65 + (e&63)] = PTb[(jc*64 + (e>>6))*256 + (e&63)];
    }
    __syncthreads();
    #pragma unroll 4
    for (int jj=0;jj<64;++jj){
      const float p = PTl[jj*65 + i];
      const float* wvr = wv + (jc*64+jj)*64 + cg*16;
      #pragma unroll
      for (int cc=0;cc<16;++cc)
        acc[cc] = fmaf(p, wvr[cc], acc[cc]);
    }
  }
  float* V1o = ws + WS_V1 + b*16384 + (iq*64+i)*64 + cg*16;
  #pragma unroll
  for (int cc=0;cc<16;++cc) V1o[cc] = acc[cc]*INV_SQRT_H;
}

// ---------------- KC: M K-partials = wc-slice @ V1-slice (R8-proven) ----------------
__global__ __launch_bounds__(256) void kc_mpart(const float* __restrict__ wc,
                                                float* __restrict__ ws){
  __shared__ float V1l[4096];
  const int b = blockIdx.y, kq = blockIdx.x;
  const int t = threadIdx.x;
  const float* Vsrc = ws + WS_V1 + b*16384 + kq*4096;
  #pragma unroll
  for (int r=0;r<16;++r) V1l[t + 256*r] = Vsrc[t + 256*r];
  __syncthreads();
  const int c = t&63;
  const int og = __builtin_amdgcn_readfirstlane(t>>6);
  float acc[16];
  #pragma unroll
  for (int oo=0;oo<16;++oo) acc[oo]=0.f;
  #pragma unroll 4
  for (int i=0;i<64;++i){
    const float v = V1l[i*64 + c];
    const float* wcr = wc + (og*16)*256 + kq*64 + i;
    #pragma unroll
    for (int oo=0;oo<16;++oo)
      acc[oo] = fmaf(wcr[oo*256], v, acc[oo]);
  }
  float* Mp = ws + WS_MPART + (b*4 + kq)*4096;
  #pragma unroll
  for (int oo=0;oo<16;++oo)
    Mp[(og*16+oo)*64 + c] = acc[oo];
}

// ---------------- KD: M rows + BN1 stats partials (R8-proven) ----------------
__global__ __launch_bounds__(256) void kd_stats1(float* __restrict__ ws){
  __shared__ float Msub[16*65];
  __shared__ float Gl[64*67];
  __shared__ float Sxl[64];
  const int b = blockIdx.y, oq = blockIdx.x;
  const int t = threadIdx.x;
  const float* Mp = ws + WS_MPART + b*4*4096 + oq*1024;
  #pragma unroll
  for (int r=0;r<4;++r){
    const int e = t + 256*r;
    const float s = Mp[e] + Mp[4096+e] + Mp[2*4096+e] + Mp[3*4096+e];
    ws[WS_M + b*4096 + oq*1024 + e] = s;
    Msub[(e>>6)*65 + (e&63)] = s;
  }
  #pragma unroll 4
  for (int r=0;r<16;++r){
    const int e = t + 256*r;
    Gl[(e>>6)*67 + (e&63)] = ws[WS_G + b*4096 + e];
  }
  if (t<64) Sxl[t] = ws[WS_SX + b*64 + t];
  __syncthreads();
  const int o = t>>4, q = t&15;
  float d = 0.f;
  #pragma unroll
  for (int kk=0;kk<4;++kk){
    const int k = q*4+kk;
    float s = 0.f;
    #pragma unroll 4
    for (int c=0;c<64;++c) s = fmaf(Gl[k*67+c], Msub[o*65+c], s);
    d = fmaf(Msub[o*65+k], s, d);
  }
  d += __shfl_xor(d, 1, 16);
  d += __shfl_xor(d, 2, 16);
  d += __shfl_xor(d, 4, 16);
  d += __shfl_xor(d, 8, 16);
  if (q==0){
    float s1 = 0.f;
    #pragma unroll 4
    for (int c=0;c<64;++c) s1 = fmaf(Msub[o*65+c], Sxl[c], s1);
    atomicAdd(&ws[WS_STATS + oq*16 + o], s1);
    atomicAdd(&ws[WS_STATS + 64 + oq*16 + o], d);
  }
}

// ---------------- KE: N rows + BN2 stats partials (R8-proven) ----------------
__global__ __launch_bounds__(256) void ke_n_stats2(const float* __restrict__ wl,
                                                   const float* __restrict__ g1,
                                                   float* __restrict__ ws){
  __shared__ float Ml[64*65];
  __shared__ float Gl[64*67];
  __shared__ float wls[16*65];
  __shared__ float Nsub[16*65];
  __shared__ float Sxl[64], a1l[64];
  const int b = blockIdx.y, oq = blockIdx.x;
  const int t = threadIdx.x;
  if (t<64){
    const float mean1 = ws[WS_STATS+t]*INV_BL;
    const float var1 = ws[WS_STATS+64+t]*INV_BL - mean1*mean1;
    a1l[t] = g1[t]*rsqrtf(var1 + EPSV);
    Sxl[t] = ws[WS_SX + b*64 + t];
  }
  #pragma unroll 4
  for (int r=0;r<16;++r){
    const int e = t + 256*r;
    Ml[(e>>6)*65 + (e&63)] = ws[WS_M + b*4096 + e];
    Gl[(e>>6)*67 + (e&63)] = ws[WS_G + b*4096 + e];
  }
  __syncthreads();
  #pragma unroll
  for (int r=0;r<4;++r){
    const int e = t + 256*r;
    wls[(e>>6)*65 + (e&63)] = wl[(oq*16 + (e>>6))*64 + (e&63)] * a1l[e&63];
  }
  __syncthreads();
  const int o = t>>4, q = t&15;
  const int row = oq*16 + o;
  {
    float acc[4];
    #pragma unroll
    for (int cc=0;cc<4;++cc) acc[cc]=0.f;
    #pragma unroll 4
    for (int k=0;k<64;++k){
      const float w = wls[o*65 + k];
      #pragma unroll
      for (int cc=0;cc<4;++cc)
        acc[cc] = fmaf(w, Ml[k*65 + q*4 + cc], acc[cc]);
    }
    #pragma unroll
    for (int cc=0;cc<4;++cc){
      const float nv = acc[cc] + wl[row*64 + q*4 + cc];
      ws[WS_N + b*4096 + o*64 + oq*1024 + q*4 + cc] = nv;
      Nsub[o*65 + q*4 + cc] = nv;
    }
  }
  __syncthreads();
  float d = 0.f;
  #pragma unroll
  for (int kk=0;kk<4;++kk){
    const int k = q*4+kk;
    float s = 0.f;
    #pragma unroll 4
    for (int c=0;c<64;++c) s = fmaf(Gl[k*67+c], Nsub[o*65+c], s);
    d = fmaf(Nsub[o*65+k], s, d);
  }
  d += __shfl_xor(d, 1, 16);
  d += __shfl_xor(d, 2, 16);
  d += __shfl_xor(d, 4, 16);
  d += __shfl_xor(d, 8, 16);
  if (q==0){
    float s2 = 0.f;
    #pragma unroll 4
    for (int c=0;c<64;++c) s2 = fmaf(Nsub[o*65+c], Sxl[c], s2);
    atomicAdd(&ws[WS_STATS + 128 + row], s2);
    atomicAdd(&ws[WS_STATS + 192 + row], d);
  }
}

// ---------------- K3: out = relu(a2*(N x) + e) ----------------
__global__ __launch_bounds__(256) void k3_out(const float* __restrict__ x,
                                              const float* __restrict__ g2,
                                              const float* __restrict__ b2,
                                              const float* __restrict__ ws,
                                              float* __restrict__ out){
  __shared__ float a2l[64], el[64];
  const int b = blockIdx.y, lc = blockIdx.x;
  const int t = threadIdx.x;
  if (t<64){
    const float mu = ws[WS_STATS+128+t]*INV_BL;
    const float var2 = ws[WS_STATS+192+t]*INV_BL - mu*mu;
    const float a2 = g2[t]*rsqrtf(var2 + EPSV);
    a2l[t] = a2;
    el[t] = b2[t] - a2*mu;
  }
  __syncthreads();
  const int w = __builtin_amdgcn_readfirstlane(t >> 6);
  const int lane = t & 63;
  const int l = lc*256 + 4*lane;
  const float* Np = ws + WS_N + b*4096 + w*1024;
  const float* xb = x + b*TC*TL + l;
  float4 acc[16];
  #pragma unroll
  for (int oo=0;oo<16;++oo){ acc[oo].x=0.f; acc[oo].y=0.f; acc[oo].z=0.f; acc[oo].w=0.f; }
  #pragma unroll 4
  for (int c=0;c<64;++c){
    const float4 xv = *(const float4*)(xb + c*TL);
    #pragma unroll
    for (int oo=0;oo<16;++oo){
      const float nv = Np[oo*64 + c];
      acc[oo].x = fmaf(nv, xv.x, acc[oo].x);
      acc[oo].y = fmaf(nv, xv.y, acc[oo].y);
      acc[oo].z = fmaf(nv, xv.z, acc[oo].z);
      acc[oo].w = fmaf(nv, xv.w, acc[oo].w);
    }
  }
  #pragma unroll
  for (int oo=0;oo<16;++oo){
    const float a2v = a2l[w*16+oo], ev = el[w*16+oo];
    float4 r;
    r.x = fmaxf(fmaf(a2v, acc[oo].x, ev), 0.f);
    r.y = fmaxf(fmaf(a2v, acc[oo].y, ev), 0.f);
    r.z = fmaxf(fmaf(a2v, acc[oo].z, ev), 0.f);
    r.w = fmaxf(fmaf(a2v, acc[oo].w, ev), 0.f);
    *(float4*)(out + (b*TC + w*16 + oo)*TL + l) = r;
  }
}

extern "C" void kernel_launch(void* const* d_in, const int* in_sizes, int n_in,
                              void* d_out, int out_size, void* d_ws, size_t ws_size,
                              hipStream_t stream){
  const float* x  = (const float*)d_in[0];
  const float* wk = (const float*)d_in[1];
  const float* wq = (const float*)d_in[2];
  const float* wv = (const float*)d_in[3];
  const float* wc = (const float*)d_in[4];
  const float* g1 = (const float*)d_in[5];
  /* b1 (d_in[6]) provably cancels through BN2 mean-subtraction */
  const float* wl = (const float*)d_in[7];
  const float* g2 = (const float*)d_in[8];
  const float* b2 = (const float*)d_in[9];
  float* out = (float*)d_out;
  float* ws  = (float*)d_ws;

  k1_gram    <<<dim3(32,16), 512, 0, stream>>>(x, ws);
  kA         <<<dim3(16,16), 256, 0, stream>>>(wq, ws);
  kb1_scores <<<dim3(16,16), 256, 0, stream>>>(wk, ws);
  kb2_v1     <<<dim3(4,16),  256, 0, stream>>>(wv, ws);
  kc_mpart   <<<dim3(4,16),  256, 0, stream>>>(wc, ws);
  kd_stats1  <<<dim3(4,16),  256, 0, stream>>>(ws);
  ke_n_stats2<<<dim3(4,16),  256, 0, stream>>>(wl, g1, ws);
  k3_out     <<<dim3(32,16), 256, 0, stream>>>(x, g2, b2, ws, out);
}

// Round 11
// 113.913 us; speedup vs baseline: 1.3827x; 1.0185x over previous
//
#include <hip/hip_runtime.h>
#include <math.h>

#define TB 16
#define TL 8192
#define TC 64

constexpr float INV_BL = 1.0f / (16.0f * 8192.0f);
constexpr float EPSV = 1e-5f;
constexpr float INV_SQRT_H = 0.17677669529663687f; // 1/sqrt(32)

// workspace offsets (floats) — ws is 256 MiB
#define WS_G      0        /* [16][64][64] */
#define WS_SX     65536    /* [16][64] */
#define WS_STATS  66560    /* s1[64] d1[64] s2[64] d2[64] */
#define WS_M      66816    /* [16][64][64] */
#define WS_N      132352   /* [16][64][64] */
#define WS_S1T    197888   /* [16][64][256] -> ends 460032 */
#define WS_V1P    460032   /* [16][16jp][64c][256i] -> ends 4654336 */
#define WS_GPART  4654336  /* [16][64][4096] -> ends 8848640 */
#define WS_SXPART 8848640  /* [16][64][64] -> ends 8914176 */
#define WS_MPART  8914176  /* [16][4][4096] -> ends 9176320 */

typedef __attribute__((ext_vector_type(8))) short short8v;  // 8 bf16 (4 VGPRs)
typedef __attribute__((ext_vector_type(4))) float f32x4;    // MFMA C/D

__device__ __forceinline__ ushort bf16rne(float f){
  uint u = __float_as_uint(f);
  u += 0x7FFF + ((u >> 16) & 1);
  return (ushort)(u >> 16);
}

// granule-swizzled address (in ushorts): tile [64 ch][128 k] bf16, granule = 8 bf16
__device__ __forceinline__ int fraddr(int ch, int g){
  return ch*128 + 8*(g ^ (ch & 7));
}

// ---------------- K1 v7: single-shot MFMA Gram, 1024 blocks ----------------
// grid (64 chunk, 16 b), 256 threads = 4 waves. One 64ch x 128l subtile per block.
// Wave w owns output row-block ti=w, all 4 tj tiles.
__global__ __launch_bounds__(256) void k1_gram(const float* __restrict__ x,
                                               float* __restrict__ ws){
  __shared__ ushort Xh[64*128];
  __shared__ ushort Xl[64*128];
  const int b = blockIdx.y, chunk = blockIdx.x;
  const int t = threadIdx.x;
  const int lane = t & 63;
  const int w = __builtin_amdgcn_readfirstlane(t >> 6);  // wave 0..3
  const float* xb = x + (size_t)b*TC*TL + (size_t)chunk*128;
  // staging: thread (ch = t>>2, q = t&3) covers l = q*32..q*32+32
  const int ch = t >> 2, q = t & 3;
  float sx = 0.f;
  #pragma unroll
  for (int gg=0; gg<4; ++gg){
    const float4 v0 = *(const float4*)(xb + ch*TL + q*32 + 8*gg);
    const float4 v1 = *(const float4*)(xb + ch*TL + q*32 + 8*gg + 4);
    const float ff[8] = {v0.x,v0.y,v0.z,v0.w,v1.x,v1.y,v1.z,v1.w};
    union { short8v v; ushort u[8]; } hh, ll;
    #pragma unroll
    for (int i=0;i<8;++i){
      sx += ff[i];
      const ushort hv = bf16rne(ff[i]);
      hh.u[i] = hv;
      ll.u[i] = bf16rne(ff[i] - __uint_as_float(((uint)hv)<<16));
    }
    const int g = q*4 + gg;
    const int wa = ch*128 + 8*(g ^ (ch & 7));
    *(short8v*)&Xh[wa] = hh.v;
    *(short8v*)&Xl[wa] = ll.v;
  }
  __syncthreads();
  // MFMA: wave w = row-block; 4 tj tiles; K=128 in 4 k-steps
  const int rA = w*16 + (lane & 15);
  const int gq = lane >> 4;
  f32x4 acc0={0.f,0.f,0.f,0.f}, acc1={0.f,0.f,0.f,0.f},
        acc2={0.f,0.f,0.f,0.f}, acc3={0.f,0.f,0.f,0.f};
  #pragma unroll
  for (int kk=0; kk<4; ++kk){
    const int g = kk*4 + gq;
    const short8v Ah = *(const short8v*)&Xh[fraddr(rA, g)];
    const short8v Al = *(const short8v*)&Xl[fraddr(rA, g)];
    const int rB = (lane & 15);
    const short8v Bh0 = *(const short8v*)&Xh[fraddr(rB,      g)];
    const short8v Bl0 = *(const short8v*)&Xl[fraddr(rB,      g)];
    const short8v Bh1 = *(const short8v*)&Xh[fraddr(rB + 16, g)];
    const short8v Bl1 = *(const short8v*)&Xl[fraddr(rB + 16, g)];
    const short8v Bh2 = *(const short8v*)&Xh[fraddr(rB + 32, g)];
    const short8v Bl2 = *(const short8v*)&Xl[fraddr(rB + 32, g)];
    const short8v Bh3 = *(const short8v*)&Xh[fraddr(rB + 48, g)];
    const short8v Bl3 = *(const short8v*)&Xl[fraddr(rB + 48, g)];
    acc0 = __builtin_amdgcn_mfma_f32_16x16x32_bf16(Ah, Bh0, acc0, 0, 0, 0);
    acc0 = __builtin_amdgcn_mfma_f32_16x16x32_bf16(Ah, Bl0, acc0, 0, 0, 0);
    acc0 = __builtin_amdgcn_mfma_f32_16x16x32_bf16(Al, Bh0, acc0, 0, 0, 0);
    acc0 = __builtin_amdgcn_mfma_f32_16x16x32_bf16(Al, Bl0, acc0, 0, 0, 0);
    acc1 = __builtin_amdgcn_mfma_f32_16x16x32_bf16(Ah, Bh1, acc1, 0, 0, 0);
    acc1 = __builtin_amdgcn_mfma_f32_16x16x32_bf16(Ah, Bl1, acc1, 0, 0, 0);
    acc1 = __builtin_amdgcn_mfma_f32_16x16x32_bf16(Al, Bh1, acc1, 0, 0, 0);
    acc1 = __builtin_amdgcn_mfma_f32_16x16x32_bf16(Al, Bl1, acc1, 0, 0, 0);
    acc2 = __builtin_amdgcn_mfma_f32_16x16x32_bf16(Ah, Bh2, acc2, 0, 0, 0);
    acc2 = __builtin_amdgcn_mfma_f32_16x16x32_bf16(Ah, Bl2, acc2, 0, 0, 0);
    acc2 = __builtin_amdgcn_mfma_f32_16x16x32_bf16(Al, Bh2, acc2, 0, 0, 0);
    acc2 = __builtin_amdgcn_mfma_f32_16x16x32_bf16(Al, Bl2, acc2, 0, 0, 0);
    acc3 = __builtin_amdgcn_mfma_f32_16x16x32_bf16(Ah, Bh3, acc3, 0, 0, 0);
    acc3 = __builtin_amdgcn_mfma_f32_16x16x32_bf16(Ah, Bl3, acc3, 0, 0, 0);
    acc3 = __builtin_amdgcn_mfma_f32_16x16x32_bf16(Al, Bh3, acc3, 0, 0, 0);
    acc3 = __builtin_amdgcn_mfma_f32_16x16x32_bf16(Al, Bl3, acc3, 0, 0, 0);
  }
  // C/D map: col=lane&15, row=(lane>>4)*4+r (m89/m91, verified R8)
  float* Gp = ws + WS_GPART + (size_t)(b*64 + chunk)*4096;
  const int col = lane & 15, rq = lane >> 4;
  #pragma unroll
  for (int r=0;r<4;++r){
    const int row = (w*16 + rq*4 + r)*64;
    Gp[row +  0 + col] = acc0[r];
    Gp[row + 16 + col] = acc1[r];
    Gp[row + 32 + col] = acc2[r];
    Gp[row + 48 + col] = acc3[r];
  }
  // Sx: reduce over the 4 q-lanes sharing each channel
  sx += __shfl_xor(sx, 1, 4);
  sx += __shfl_xor(sx, 2, 4);
  if (q == 0){
    ws[WS_SXPART + (b*64+chunk)*64 + ch] = sx;
  }
}

// ---------------- KA: fused G/Sx reduce + S1^T columns ----------------
__global__ __launch_bounds__(256) void kA(const float* __restrict__ wq,
                                          float* __restrict__ ws){
  __shared__ float gcol[64*5];
  __shared__ float wqL[256*17];
  const int b = blockIdx.y, cq = blockIdx.x;
  const int t = threadIdx.x;
  const int k = t>>2, cj = t&3;
  const int c = 4*cq + cj;
  {
    const float* Gp = ws + WS_GPART + (size_t)b*64*4096 + k*64 + c;
    float s = 0.f;
    #pragma unroll 8
    for (int ch=0; ch<64; ++ch) s += Gp[(size_t)ch*4096];
    ws[WS_G + b*4096 + k*64 + c] = s;
    gcol[k*5 + cj] = s;
  }
  if (cq==0){
    if (t<64){
      float sv = 0.f;
      #pragma unroll 8
      for (int ch=0; ch<64; ++ch) sv += ws[WS_SXPART + (b*64+ch)*64 + t];
      ws[WS_SX + b*64 + t] = sv;
    }
    if (b==0) ws[WS_STATS + t] = 0.f;
  }
  __syncthreads();
  float sc0=0.f, sc1=0.f, sc2=0.f, sc3=0.f;
  for (int ic=0; ic<4; ++ic){
    if (ic) __syncthreads();
    #pragma unroll
    for (int r=0;r<16;++r){
      const int e = t + 256*r;
      wqL[(e>>4)*17 + (e&15)] = wq[(e>>4)*64 + ic*16 + (e&15)];
    }
    __syncthreads();
    #pragma unroll
    for (int kk=0; kk<16; ++kk){
      const float wv = wqL[t*17 + kk];
      const int kg = ic*16 + kk;
      sc0 = fmaf(wv, gcol[kg*5+0], sc0);
      sc1 = fmaf(wv, gcol[kg*5+1], sc1);
      sc2 = fmaf(wv, gcol[kg*5+2], sc2);
      sc3 = fmaf(wv, gcol[kg*5+3], sc3);
    }
  }
  float* S1T = ws + WS_S1T + b*16384;
  S1T[(4*cq+0)*256 + t] = sc0;
  S1T[(4*cq+1)*256 + t] = sc1;
  S1T[(4*cq+2)*256 + t] = sc2;
  S1T[(4*cq+3)*256 + t] = sc3;
}

// ---------------- KB12: scores + column softmax + PV partial (fused) ----------------
// grid (16 jp, 16 b). Phase A = proven kb1; Phase B: thread t = row t, wv via s_loads.
__global__ __launch_bounds__(256) void kb12(const float* __restrict__ wk,
                                            const float* __restrict__ wv,
                                            float* __restrict__ ws){
  __shared__ float scl[256*17];
  __shared__ float pstat[256];
  __shared__ float fstat[32];
  const int b = blockIdx.y, jp = blockIdx.x;
  const int j0 = jp*16;
  const int t = threadIdx.x;
  const float* S1Tb = ws + WS_S1T + b*16384;
  float sc[16];
  #pragma unroll
  for (int jj=0;jj<16;++jj) sc[jj]=0.f;
  #pragma unroll 2
  for (int k=0;k<64;++k){
    const float s1 = S1Tb[k*256 + t];
    const float* wkr = wk + j0*64 + k;
    #pragma unroll
    for (int jj=0;jj<16;++jj)
      sc[jj] = fmaf(wkr[jj*64], s1, sc[jj]);
  }
  #pragma unroll
  for (int jj=0;jj<16;++jj) scl[t*17+jj] = sc[jj];
  __syncthreads();
  const int col = t&15, ig = t>>4;
  {
    float m = -3.0e38f;
    #pragma unroll
    for (int q=0;q<16;++q) m = fmaxf(m, scl[(ig*16+q)*17 + col]);
    pstat[ig*16+col] = m;
  }
  __syncthreads();
  if (t<16){
    float m = -3.0e38f;
    #pragma unroll
    for (int q=0;q<16;++q) m = fmaxf(m, pstat[q*16+t]);
    fstat[t] = m;
  }
  __syncthreads();
  {
    const float mj = fstat[col];
    float s = 0.f;
    #pragma unroll
    for (int q=0;q<16;++q) s += __expf(scl[(ig*16+q)*17 + col] - mj);
    pstat[ig*16+col] = s;
  }
  __syncthreads();
  if (t<16){
    float s = 0.f;
    #pragma unroll
    for (int q=0;q<16;++q) s += pstat[q*16+t];
    fstat[16+t] = 1.f/s;
  }
  __syncthreads();
  // normalize in-register
  #pragma unroll
  for (int jj=0;jj<16;++jj)
    sc[jj] = __expf(sc[jj] - fstat[jj]) * fstat[16+jj];
  // PV partial: row t, 4 passes of 16 c; wv rows wave-uniform -> s_load
  float* Vp = ws + WS_V1P + (size_t)(b*16 + jp)*16384;
  for (int cb=0; cb<4; ++cb){
    float acc[16];
    #pragma unroll
    for (int cc=0;cc<16;++cc) acc[cc]=0.f;
    #pragma unroll
    for (int jj=0;jj<16;++jj){
      const float p = sc[jj];
      const float* wvr = wv + (j0+jj)*64 + cb*16;  // uniform -> s_load
      #pragma unroll
      for (int cc=0;cc<16;++cc)
        acc[cc] = fmaf(p, wvr[cc], acc[cc]);
    }
    #pragma unroll
    for (int cc=0;cc<16;++cc)
      Vp[(cb*16+cc)*256 + t] = acc[cc];       // [c][row], coalesced
  }
}

// ---------------- KC: sum V1 partials + M K-partials ----------------
// grid (4 kq, 16 b)
__global__ __launch_bounds__(256) void kc_mpart(const float* __restrict__ wc,
                                                float* __restrict__ ws){
  __shared__ float V1l[64*65];   // [ii][c] stride 65
  const int b = blockIdx.y, kq = blockIdx.x;
  const int t = threadIdx.x;
  #pragma unroll
  for (int r=0;r<16;++r){
    const int e = t + 256*r;
    const int c = e>>6, ii = e&63;
    const float* Vp = ws + WS_V1P + (size_t)b*16*16384 + c*256 + kq*64 + ii;
    float s = 0.f;
    #pragma unroll
    for (int jp=0;jp<16;++jp) s += Vp[jp*16384];
    V1l[ii*65 + c] = s * INV_SQRT_H;
  }
  __syncthreads();
  const int c = t&63;
  const int og = __builtin_amdgcn_readfirstlane(t>>6);
  float acc[16];
  #pragma unroll
  for (int oo=0;oo<16;++oo) acc[oo]=0.f;
  #pragma unroll 4
  for (int i=0;i<64;++i){
    const float v = V1l[i*65 + c];
    const float* wcr = wc + (og*16)*256 + kq*64 + i;  // uniform -> s_load
    #pragma unroll
    for (int oo=0;oo<16;++oo)
      acc[oo] = fmaf(wcr[oo*256], v, acc[oo]);
  }
  float* Mp = ws + WS_MPART + (b*4 + kq)*4096;
  #pragma unroll
  for (int oo=0;oo<16;++oo)
    Mp[(og*16+oo)*64 + c] = acc[oo];
}

// ---------------- KD: M rows + BN1 stats partials (R8-proven) ----------------
__global__ __launch_bounds__(256) void kd_stats1(float* __restrict__ ws){
  __shared__ float Msub[16*65];
  __shared__ float Gl[64*67];
  __shared__ float Sxl[64];
  const int b = blockIdx.y, oq = blockIdx.x;
  const int t = threadIdx.x;
  const float* Mp = ws + WS_MPART + b*4*4096 + oq*1024;
  #pragma unroll
  for (int r=0;r<4;++r){
    const int e = t + 256*r;
    const float s = Mp[e] + Mp[4096+e] + Mp[2*4096+e] + Mp[3*4096+e];
    ws[WS_M + b*4096 + oq*1024 + e] = s;
    Msub[(e>>6)*65 + (e&63)] = s;
  }
  #pragma unroll 4
  for (int r=0;r<16;++r){
    const int e = t + 256*r;
    Gl[(e>>6)*67 + (e&63)] = ws[WS_G + b*4096 + e];
  }
  if (t<64) Sxl[t] = ws[WS_SX + b*64 + t];
  __syncthreads();
  const int o = t>>4, q = t&15;
  float d = 0.f;
  #pragma unroll
  for (int kk=0;kk<4;++kk){
    const int k = q*4+kk;
    float s = 0.f;
    #pragma unroll 4
    for (int c=0;c<64;++c) s = fmaf(Gl[k*67+c], Msub[o*65+c], s);
    d = fmaf(Msub[o*65+k], s, d);
  }
  d += __shfl_xor(d, 1, 16);
  d += __shfl_xor(d, 2, 16);
  d += __shfl_xor(d, 4, 16);
  d += __shfl_xor(d, 8, 16);
  if (q==0){
    float s1 = 0.f;
    #pragma unroll 4
    for (int c=0;c<64;++c) s1 = fmaf(Msub[o*65+c], Sxl[c], s1);
    atomicAdd(&ws[WS_STATS + oq*16 + o], s1);
    atomicAdd(&ws[WS_STATS + 64 + oq*16 + o], d);
  }
}

// ---------------- KE: N rows + BN2 stats partials (R8-proven) ----------------
__global__ __launch_bounds__(256) void ke_n_stats2(const float* __restrict__ wl,
                                                   const float* __restrict__ g1,
                                                   float* __restrict__ ws){
  __shared__ float Ml[64*65];
  __shared__ float Gl[64*67];
  __shared__ float wls[16*65];
  __shared__ float Nsub[16*65];
  __shared__ float Sxl[64], a1l[64];
  const int b = blockIdx.y, oq = blockIdx.x;
  const int t = threadIdx.x;
  if (t<64){
    const float mean1 = ws[WS_STATS+t]*INV_BL;
    const float var1 = ws[WS_STATS+64+t]*INV_BL - mean1*mean1;
    a1l[t] = g1[t]*rsqrtf(var1 + EPSV);
    Sxl[t] = ws[WS_SX + b*64 + t];
  }
  #pragma unroll 4
  for (int r=0;r<16;++r){
    const int e = t + 256*r;
    Ml[(e>>6)*65 + (e&63)] = ws[WS_M + b*4096 + e];
    Gl[(e>>6)*67 + (e&63)] = ws[WS_G + b*4096 + e];
  }
  __syncthreads();
  #pragma unroll
  for (int r=0;r<4;++r){
    const int e = t + 256*r;
    wls[(e>>6)*65 + (e&63)] = wl[(oq*16 + (e>>6))*64 + (e&63)] * a1l[e&63];
  }
  __syncthreads();
  const int o = t>>4, q = t&15;
  const int row = oq*16 + o;
  {
    float acc[4];
    #pragma unroll
    for (int cc=0;cc<4;++cc) acc[cc]=0.f;
    #pragma unroll 4
    for (int k=0;k<64;++k){
      const float w = wls[o*65 + k];
      #pragma unroll
      for (int cc=0;cc<4;++cc)
        acc[cc] = fmaf(w, Ml[k*65 + q*4 + cc], acc[cc]);
    }
    #pragma unroll
    for (int cc=0;cc<4;++cc){
      const float nv = acc[cc] + wl[row*64 + q*4 + cc];
      ws[WS_N + b*4096 + o*64 + oq*1024 + q*4 + cc] = nv;
      Nsub[o*65 + q*4 + cc] = nv;
    }
  }
  __syncthreads();
  float d = 0.f;
  #pragma unroll
  for (int kk=0;kk<4;++kk){
    const int k = q*4+kk;
    float s = 0.f;
    #pragma unroll 4
    for (int c=0;c<64;++c) s = fmaf(Gl[k*67+c], Nsub[o*65+c], s);
    d = fmaf(Nsub[o*65+k], s, d);
  }
  d += __shfl_xor(d, 1, 16);
  d += __shfl_xor(d, 2, 16);
  d += __shfl_xor(d, 4, 16);
  d += __shfl_xor(d, 8, 16);
  if (q==0){
    float s2 = 0.f;
    #pragma unroll 4
    for (int c=0;c<64;++c) s2 = fmaf(Nsub[o*65+c], Sxl[c], s2);
    atomicAdd(&ws[WS_STATS + 128 + row], s2);
    atomicAdd(&ws[WS_STATS + 192 + row], d);
  }
}

// ---------------- K3: out = relu(a2*(N x) + e) ----------------
__global__ __launch_bounds__(256) void k3_out(const float* __restrict__ x,
                                              const float* __restrict__ g2,
                                              const float* __restrict__ b2,
                                              const float* __restrict__ ws,
                                              float* __restrict__ out){
  __shared__ float a2l[64], el[64];
  const int b = blockIdx.y, lc = blockIdx.x;
  const int t = threadIdx.x;
  if (t<64){
    const float mu = ws[WS_STATS+128+t]*INV_BL;
    const float var2 = ws[WS_STATS+192+t]*INV_BL - mu*mu;
    const float a2 = g2[t]*rsqrtf(var2 + EPSV);
    a2l[t] = a2;
    el[t] = b2[t] - a2*mu;
  }
  __syncthreads();
  const int w = __builtin_amdgcn_readfirstlane(t >> 6);
  const int lane = t & 63;
  const int l = lc*256 + 4*lane;
  const float* Np = ws + WS_N + b*4096 + w*1024;
  const float* xb = x + b*TC*TL + l;
  float4 acc[16];
  #pragma unroll
  for (int oo=0;oo<16;++oo){ acc[oo].x=0.f; acc[oo].y=0.f; acc[oo].z=0.f; acc[oo].w=0.f; }
  #pragma unroll 4
  for (int c=0;c<64;++c){
    const float4 xv = *(const float4*)(xb + c*TL);
    #pragma unroll
    for (int oo=0;oo<16;++oo){
      const float nv = Np[oo*64 + c];
      acc[oo].x = fmaf(nv, xv.x, acc[oo].x);
      acc[oo].y = fmaf(nv, xv.y, acc[oo].y);
      acc[oo].z = fmaf(nv, xv.z, acc[oo].z);
      acc[oo].w = fmaf(nv, xv.w, acc[oo].w);
    }
  }
  #pragma unroll
  for (int oo=0;oo<16;++oo){
    const float a2v = a2l[w*16+oo], ev = el[w*16+oo];
    float4 r;
    r.x = fmaxf(fmaf(a2v, acc[oo].x, ev), 0.f);
    r.y = fmaxf(fmaf(a2v, acc[oo].y, ev), 0.f);
    r.z = fmaxf(fmaf(a2v, acc[oo].z, ev), 0.f);
    r.w = fmaxf(fmaf(a2v, acc[oo].w, ev), 0.f);
    *(float4*)(out + (b*TC + w*16 + oo)*TL + l) = r;
  }
}

extern "C" void kernel_launch(void* const* d_in, const int* in_sizes, int n_in,
                              void* d_out, int out_size, void* d_ws, size_t ws_size,
                              hipStream_t stream){
  const float* x  = (const float*)d_in[0];
  const float* wk = (const float*)d_in[1];
  const float* wq = (const float*)d_in[2];
  const float* wv = (const float*)d_in[3];
  const float* wc = (const float*)d_in[4];
  const float* g1 = (const float*)d_in[5];
  /* b1 (d_in[6]) provably cancels through BN2 mean-subtraction */
  const float* wl = (const float*)d_in[7];
  const float* g2 = (const float*)d_in[8];
  const float* b2 = (const float*)d_in[9];
  float* out = (float*)d_out;
  float* ws  = (float*)d_ws;

  k1_gram    <<<dim3(64,16), 256, 0, stream>>>(x, ws);
  kA         <<<dim3(16,16), 256, 0, stream>>>(wq, ws);
  kb12       <<<dim3(16,16), 256, 0, stream>>>(wk, wv, ws);
  kc_mpart   <<<dim3(4,16),  256, 0, stream>>>(wc, ws);
  kd_stats1  <<<dim3(4,16),  256, 0, stream>>>(ws);
  ke_n_stats2<<<dim3(4,16),  256, 0, stream>>>(wl, g1, ws);
  k3_out     <<<dim3(32,16), 256, 0, stream>>>(x, g2, b2, ws, out);
}

// Round 12
// 111.578 us; speedup vs baseline: 1.4116x; 1.0209x over previous
//
#include <hip/hip_runtime.h>
#include <math.h>

#define TB 16
#define TL 8192
#define TC 64

constexpr float INV_BL = 1.0f / (16.0f * 8192.0f);
constexpr float EPSV = 1e-5f;
constexpr float INV_SQRT_H = 0.17677669529663687f; // 1/sqrt(32)

// workspace offsets (floats) — ws is 256 MiB
#define WS_G      0        /* [16][64][64] */
#define WS_SX     65536    /* [16][64] */
#define WS_STATS  66560    /* s1[64] d1[64] s2[64] d2[64] */
#define WS_M      66816    /* [16][64][64] */
#define WS_N      132352   /* [16][64][64] */
#define WS_S1T    197888   /* [16][64][256] -> ends 460032 */
#define WS_V1P    460032   /* [16][16jp][64c][256i] -> ends 4654336 */
#define WS_GPART  4654336  /* [16][64][4096] -> ends 8848640 */
#define WS_SXPART 8848640  /* [16][64][64] -> ends 8914176 */
#define WS_MPART  8914176  /* [16][16][4096] -> ends 9962752 */

typedef __attribute__((ext_vector_type(8))) short short8v;  // 8 bf16 (4 VGPRs)
typedef __attribute__((ext_vector_type(4))) float f32x4;    // MFMA C/D

__device__ __forceinline__ ushort bf16rne(float f){
  uint u = __float_as_uint(f);
  u += 0x7FFF + ((u >> 16) & 1);
  return (ushort)(u >> 16);
}

// granule-swizzled address (in ushorts): tile [64 ch][128 k] bf16, granule = 8 bf16
__device__ __forceinline__ int fraddr(int ch, int g){
  return ch*128 + 8*(g ^ (ch & 7));
}

// ---------------- K1 v7: single-shot MFMA Gram, 1024 blocks ----------------
__global__ __launch_bounds__(256) void k1_gram(const float* __restrict__ x,
                                               float* __restrict__ ws){
  __shared__ ushort Xh[64*128];
  __shared__ ushort Xl[64*128];
  const int b = blockIdx.y, chunk = blockIdx.x;
  const int t = threadIdx.x;
  const int lane = t & 63;
  const int w = __builtin_amdgcn_readfirstlane(t >> 6);  // wave 0..3
  const float* xb = x + (size_t)b*TC*TL + (size_t)chunk*128;
  const int ch = t >> 2, q = t & 3;
  float sx = 0.f;
  #pragma unroll
  for (int gg=0; gg<4; ++gg){
    const float4 v0 = *(const float4*)(xb + ch*TL + q*32 + 8*gg);
    const float4 v1 = *(const float4*)(xb + ch*TL + q*32 + 8*gg + 4);
    const float ff[8] = {v0.x,v0.y,v0.z,v0.w,v1.x,v1.y,v1.z,v1.w};
    union { short8v v; ushort u[8]; } hh, ll;
    #pragma unroll
    for (int i=0;i<8;++i){
      sx += ff[i];
      const ushort hv = bf16rne(ff[i]);
      hh.u[i] = hv;
      ll.u[i] = bf16rne(ff[i] - __uint_as_float(((uint)hv)<<16));
    }
    const int g = q*4 + gg;
    const int wa = ch*128 + 8*(g ^ (ch & 7));
    *(short8v*)&Xh[wa] = hh.v;
    *(short8v*)&Xl[wa] = ll.v;
  }
  __syncthreads();
  const int rA = w*16 + (lane & 15);
  const int gq = lane >> 4;
  f32x4 acc0={0.f,0.f,0.f,0.f}, acc1={0.f,0.f,0.f,0.f},
        acc2={0.f,0.f,0.f,0.f}, acc3={0.f,0.f,0.f,0.f};
  #pragma unroll
  for (int kk=0; kk<4; ++kk){
    const int g = kk*4 + gq;
    const short8v Ah = *(const short8v*)&Xh[fraddr(rA, g)];
    const short8v Al = *(const short8v*)&Xl[fraddr(rA, g)];
    const int rB = (lane & 15);
    const short8v Bh0 = *(const short8v*)&Xh[fraddr(rB,      g)];
    const short8v Bl0 = *(const short8v*)&Xl[fraddr(rB,      g)];
    const short8v Bh1 = *(const short8v*)&Xh[fraddr(rB + 16, g)];
    const short8v Bl1 = *(const short8v*)&Xl[fraddr(rB + 16, g)];
    const short8v Bh2 = *(const short8v*)&Xh[fraddr(rB + 32, g)];
    const short8v Bl2 = *(const short8v*)&Xl[fraddr(rB + 32, g)];
    const short8v Bh3 = *(const short8v*)&Xh[fraddr(rB + 48, g)];
    const short8v Bl3 = *(const short8v*)&Xl[fraddr(rB + 48, g)];
    acc0 = __builtin_amdgcn_mfma_f32_16x16x32_bf16(Ah, Bh0, acc0, 0, 0, 0);
    acc0 = __builtin_amdgcn_mfma_f32_16x16x32_bf16(Ah, Bl0, acc0, 0, 0, 0);
    acc0 = __builtin_amdgcn_mfma_f32_16x16x32_bf16(Al, Bh0, acc0, 0, 0, 0);
    acc0 = __builtin_amdgcn_mfma_f32_16x16x32_bf16(Al, Bl0, acc0, 0, 0, 0);
    acc1 = __builtin_amdgcn_mfma_f32_16x16x32_bf16(Ah, Bh1, acc1, 0, 0, 0);
    acc1 = __builtin_amdgcn_mfma_f32_16x16x32_bf16(Ah, Bl1, acc1, 0, 0, 0);
    acc1 = __builtin_amdgcn_mfma_f32_16x16x32_bf16(Al, Bh1, acc1, 0, 0, 0);
    acc1 = __builtin_amdgcn_mfma_f32_16x16x32_bf16(Al, Bl1, acc1, 0, 0, 0);
    acc2 = __builtin_amdgcn_mfma_f32_16x16x32_bf16(Ah, Bh2, acc2, 0, 0, 0);
    acc2 = __builtin_amdgcn_mfma_f32_16x16x32_bf16(Ah, Bl2, acc2, 0, 0, 0);
    acc2 = __builtin_amdgcn_mfma_f32_16x16x32_bf16(Al, Bh2, acc2, 0, 0, 0);
    acc2 = __builtin_amdgcn_mfma_f32_16x16x32_bf16(Al, Bl2, acc2, 0, 0, 0);
    acc3 = __builtin_amdgcn_mfma_f32_16x16x32_bf16(Ah, Bh3, acc3, 0, 0, 0);
    acc3 = __builtin_amdgcn_mfma_f32_16x16x32_bf16(Ah, Bl3, acc3, 0, 0, 0);
    acc3 = __builtin_amdgcn_mfma_f32_16x16x32_bf16(Al, Bh3, acc3, 0, 0, 0);
    acc3 = __builtin_amdgcn_mfma_f32_16x16x32_bf16(Al, Bl3, acc3, 0, 0, 0);
  }
  float* Gp = ws + WS_GPART + (size_t)(b*64 + chunk)*4096;
  const int col = lane & 15, rq = lane >> 4;
  #pragma unroll
  for (int r=0;r<4;++r){
    const int row = (w*16 + rq*4 + r)*64;
    Gp[row +  0 + col] = acc0[r];
    Gp[row + 16 + col] = acc1[r];
    Gp[row + 32 + col] = acc2[r];
    Gp[row + 48 + col] = acc3[r];
  }
  sx += __shfl_xor(sx, 1, 4);
  sx += __shfl_xor(sx, 2, 4);
  if (q == 0){
    ws[WS_SXPART + (b*64+chunk)*64 + ch] = sx;
  }
}

// ---------------- KA: fused G/Sx reduce + S1^T columns ----------------
__global__ __launch_bounds__(256) void kA(const float* __restrict__ wq,
                                          float* __restrict__ ws){
  __shared__ float gcol[64*5];
  __shared__ float wqL[256*17];
  const int b = blockIdx.y, cq = blockIdx.x;
  const int t = threadIdx.x;
  const int k = t>>2, cj = t&3;
  const int c = 4*cq + cj;
  {
    const float* Gp = ws + WS_GPART + (size_t)b*64*4096 + k*64 + c;
    float s = 0.f;
    #pragma unroll 8
    for (int ch=0; ch<64; ++ch) s += Gp[(size_t)ch*4096];
    ws[WS_G + b*4096 + k*64 + c] = s;
    gcol[k*5 + cj] = s;
  }
  if (cq==0){
    if (t<64){
      float sv = 0.f;
      #pragma unroll 8
      for (int ch=0; ch<64; ++ch) sv += ws[WS_SXPART + (b*64+ch)*64 + t];
      ws[WS_SX + b*64 + t] = sv;
    }
    if (b==0) ws[WS_STATS + t] = 0.f;
  }
  __syncthreads();
  float sc0=0.f, sc1=0.f, sc2=0.f, sc3=0.f;
  for (int ic=0; ic<4; ++ic){
    if (ic) __syncthreads();
    #pragma unroll
    for (int r=0;r<16;++r){
      const int e = t + 256*r;
      wqL[(e>>4)*17 + (e&15)] = wq[(e>>4)*64 + ic*16 + (e&15)];
    }
    __syncthreads();
    #pragma unroll
    for (int kk=0; kk<16; ++kk){
      const float wv = wqL[t*17 + kk];
      const int kg = ic*16 + kk;
      sc0 = fmaf(wv, gcol[kg*5+0], sc0);
      sc1 = fmaf(wv, gcol[kg*5+1], sc1);
      sc2 = fmaf(wv, gcol[kg*5+2], sc2);
      sc3 = fmaf(wv, gcol[kg*5+3], sc3);
    }
  }
  float* S1T = ws + WS_S1T + b*16384;
  S1T[(4*cq+0)*256 + t] = sc0;
  S1T[(4*cq+1)*256 + t] = sc1;
  S1T[(4*cq+2)*256 + t] = sc2;
  S1T[(4*cq+3)*256 + t] = sc3;
}

// ---------------- KB12: scores + column softmax + PV partial (fused) ----------------
__global__ __launch_bounds__(256) void kb12(const float* __restrict__ wk,
                                            const float* __restrict__ wv,
                                            float* __restrict__ ws){
  __shared__ float scl[256*17];
  __shared__ float pstat[256];
  __shared__ float fstat[32];
  const int b = blockIdx.y, jp = blockIdx.x;
  const int j0 = jp*16;
  const int t = threadIdx.x;
  const float* S1Tb = ws + WS_S1T + b*16384;
  float sc[16];
  #pragma unroll
  for (int jj=0;jj<16;++jj) sc[jj]=0.f;
  #pragma unroll 2
  for (int k=0;k<64;++k){
    const float s1 = S1Tb[k*256 + t];
    const float* wkr = wk + j0*64 + k;
    #pragma unroll
    for (int jj=0;jj<16;++jj)
      sc[jj] = fmaf(wkr[jj*64], s1, sc[jj]);
  }
  #pragma unroll
  for (int jj=0;jj<16;++jj) scl[t*17+jj] = sc[jj];
  __syncthreads();
  const int col = t&15, ig = t>>4;
  {
    float m = -3.0e38f;
    #pragma unroll
    for (int q=0;q<16;++q) m = fmaxf(m, scl[(ig*16+q)*17 + col]);
    pstat[ig*16+col] = m;
  }
  __syncthreads();
  if (t<16){
    float m = -3.0e38f;
    #pragma unroll
    for (int q=0;q<16;++q) m = fmaxf(m, pstat[q*16+t]);
    fstat[t] = m;
  }
  __syncthreads();
  {
    const float mj = fstat[col];
    float s = 0.f;
    #pragma unroll
    for (int q=0;q<16;++q) s += __expf(scl[(ig*16+q)*17 + col] - mj);
    pstat[ig*16+col] = s;
  }
  __syncthreads();
  if (t<16){
    float s = 0.f;
    #pragma unroll
    for (int q=0;q<16;++q) s += pstat[q*16+t];
    fstat[16+t] = 1.f/s;
  }
  __syncthreads();
  #pragma unroll
  for (int jj=0;jj<16;++jj)
    sc[jj] = __expf(sc[jj] - fstat[jj]) * fstat[16+jj];
  float* Vp = ws + WS_V1P + (size_t)(b*16 + jp)*16384;
  for (int cb=0; cb<4; ++cb){
    float acc[16];
    #pragma unroll
    for (int cc=0;cc<16;++cc) acc[cc]=0.f;
    #pragma unroll
    for (int jj=0;jj<16;++jj){
      const float p = sc[jj];
      const float* wvr = wv + (j0+jj)*64 + cb*16;  // uniform -> s_load
      #pragma unroll
      for (int cc=0;cc<16;++cc)
        acc[cc] = fmaf(p, wvr[cc], acc[cc]);
    }
    #pragma unroll
    for (int cc=0;cc<16;++cc)
      Vp[(cb*16+cc)*256 + t] = acc[cc];       // [c][row], coalesced
  }
}

// ---------------- KC v2: sum V1 partials (16-row slice) + M K-partials; 256 blocks ----------------
// grid (16 kq, 16 b): block owns V1 rows i in [kq*16, +16).
__global__ __launch_bounds__(256) void kc_mpart(const float* __restrict__ wc,
                                                float* __restrict__ ws){
  __shared__ float V1l[16*65];   // [il][c] stride 65
  const int b = blockIdx.y, kq = blockIdx.x;
  const int t = threadIdx.x;
  #pragma unroll
  for (int r=0;r<4;++r){
    const int e = t + 256*r;          // 1024 elements: il = e&15, c = e>>4
    const int il = e & 15, c = e >> 4;
    const float* Vp = ws + WS_V1P + (size_t)b*16*16384 + c*256 + kq*16 + il;
    float s = 0.f;
    #pragma unroll
    for (int jp=0;jp<16;++jp) s += Vp[jp*16384];
    V1l[il*65 + c] = s * INV_SQRT_H;
  }
  __syncthreads();
  const int c = t & 63;
  const int og = __builtin_amdgcn_readfirstlane(t >> 6);
  float acc[16];
  #pragma unroll
  for (int oo=0;oo<16;++oo) acc[oo]=0.f;
  #pragma unroll
  for (int il=0; il<16; ++il){
    const float v = V1l[il*65 + c];
    const float* wcr = wc + (og*16)*256 + kq*16 + il;  // uniform -> s_load
    #pragma unroll
    for (int oo=0;oo<16;++oo)
      acc[oo] = fmaf(wcr[oo*256], v, acc[oo]);
  }
  float* Mp = ws + WS_MPART + (size_t)(b*16 + kq)*4096;
  #pragma unroll
  for (int oo=0;oo<16;++oo)
    Mp[(og*16+oo)*64 + c] = acc[oo];
}

// ---------------- KD v2: M rows + BN1 stats; 256 blocks, wave-per-row ----------------
// grid (16 oq, 16 b): block owns M rows [oq*4, +4), one wave each.
__global__ __launch_bounds__(256) void kd_stats1(float* __restrict__ ws){
  __shared__ float Msub[4*65];
  __shared__ float Gl[64*67];
  __shared__ float Sxl[64];
  const int b = blockIdx.y, oq = blockIdx.x;
  const int t = threadIdx.x;
  const int o = t >> 6, lane = t & 63;
  const int row = oq*4 + o;
  {
    const float* Mp = ws + WS_MPART + (size_t)b*16*4096 + row*64 + lane;
    float s = 0.f;
    #pragma unroll
    for (int kq=0;kq<16;++kq) s += Mp[kq*4096];
    ws[WS_M + b*4096 + row*64 + lane] = s;
    Msub[o*65 + lane] = s;
  }
  #pragma unroll
  for (int r=0;r<16;++r){
    const int e = t + 256*r;
    Gl[(e>>6)*67 + (e&63)] = ws[WS_G + b*4096 + e];
  }
  if (t<64) Sxl[t] = ws[WS_SX + b*64 + t];
  __syncthreads();
  // lane k: s_k = sum_c G[k][c]*M[row][c]; d = sum_k M[row][k]*s_k
  float sk = 0.f;
  #pragma unroll 4
  for (int c=0;c<64;++c) sk = fmaf(Gl[lane*67+c], Msub[o*65+c], sk);
  float d = Msub[o*65 + lane] * sk;
  float s1 = Msub[o*65 + lane] * Sxl[lane];
  #pragma unroll
  for (int off=1; off<64; off<<=1){
    d  += __shfl_xor(d,  off);
    s1 += __shfl_xor(s1, off);
  }
  if (lane==0){
    atomicAdd(&ws[WS_STATS + row], s1);
    atomicAdd(&ws[WS_STATS + 64 + row], d);
  }
}

// ---------------- KE v2: N rows + BN2 stats; 256 blocks, wave-per-row ----------------
// grid (16 oq, 16 b)
__global__ __launch_bounds__(256) void ke_n_stats2(const float* __restrict__ wl,
                                                   const float* __restrict__ g1,
                                                   float* __restrict__ ws){
  __shared__ float Ml[64*65];
  __shared__ float Gl[64*67];
  __shared__ float Nsub[4*65];
  __shared__ float Sxl[64], a1l[64];
  const int b = blockIdx.y, oq = blockIdx.x;
  const int t = threadIdx.x;
  const int o = t >> 6, lane = t & 63;
  const int row = oq*4 + o;
  if (t<64){
    const float mean1 = ws[WS_STATS+t]*INV_BL;
    const float var1 = ws[WS_STATS+64+t]*INV_BL - mean1*mean1;
    a1l[t] = g1[t]*rsqrtf(var1 + EPSV);
    Sxl[t] = ws[WS_SX + b*64 + t];
  }
  #pragma unroll
  for (int r=0;r<16;++r){
    const int e = t + 256*r;
    Ml[(e>>6)*65 + (e&63)] = ws[WS_M + b*4096 + e];
    Gl[(e>>6)*67 + (e&63)] = ws[WS_G + b*4096 + e];
  }
  __syncthreads();
  // N[row][c] = sum_k wl[row][k]*a1[k]*M[k][c] + wl[row][c]
  float acc = 0.f;
  #pragma unroll 4
  for (int k=0;k<64;++k){
    const float wk_ = wl[row*64 + k] * a1l[k];   // s_load * LDS broadcast
    acc = fmaf(wk_, Ml[k*65 + lane], acc);
  }
  const float nv = acc + wl[row*64 + lane];
  ws[WS_N + b*4096 + row*64 + lane] = nv;
  Nsub[o*65 + lane] = nv;
  __syncthreads();
  float sk = 0.f;
  #pragma unroll 4
  for (int c=0;c<64;++c) sk = fmaf(Gl[lane*67+c], Nsub[o*65+c], sk);
  float d = Nsub[o*65 + lane] * sk;
  float s2 = Nsub[o*65 + lane] * Sxl[lane];
  #pragma unroll
  for (int off=1; off<64; off<<=1){
    d  += __shfl_xor(d,  off);
    s2 += __shfl_xor(s2, off);
  }
  if (lane==0){
    atomicAdd(&ws[WS_STATS + 128 + row], s2);
    atomicAdd(&ws[WS_STATS + 192 + row], d);
  }
}

// ---------------- K3: out = relu(a2*(N x) + e) ----------------
__global__ __launch_bounds__(256) void k3_out(const float* __restrict__ x,
                                              const float* __restrict__ g2,
                                              const float* __restrict__ b2,
                                              const float* __restrict__ ws,
                                              float* __restrict__ out){
  __shared__ float a2l[64], el[64];
  const int b = blockIdx.y, lc = blockIdx.x;
  const int t = threadIdx.x;
  if (t<64){
    const float mu = ws[WS_STATS+128+t]*INV_BL;
    const float var2 = ws[WS_STATS+192+t]*INV_BL - mu*mu;
    const float a2 = g2[t]*rsqrtf(var2 + EPSV);
    a2l[t] = a2;
    el[t] = b2[t] - a2*mu;
  }
  __syncthreads();
  const int w = __builtin_amdgcn_readfirstlane(t >> 6);
  const int lane = t & 63;
  const int l = lc*256 + 4*lane;
  const float* Np = ws + WS_N + b*4096 + w*1024;
  const float* xb = x + b*TC*TL + l;
  float4 acc[16];
  #pragma unroll
  for (int oo=0;oo<16;++oo){ acc[oo].x=0.f; acc[oo].y=0.f; acc[oo].z=0.f; acc[oo].w=0.f; }
  #pragma unroll 4
  for (int c=0;c<64;++c){
    const float4 xv = *(const float4*)(xb + c*TL);
    #pragma unroll
    for (int oo=0;oo<16;++oo){
      const float nv = Np[oo*64 + c];
      acc[oo].x = fmaf(nv, xv.x, acc[oo].x);
      acc[oo].y = fmaf(nv, xv.y, acc[oo].y);
      acc[oo].z = fmaf(nv, xv.z, acc[oo].z);
      acc[oo].w = fmaf(nv, xv.w, acc[oo].w);
    }
  }
  #pragma unroll
  for (int oo=0;oo<16;++oo){
    const float a2v = a2l[w*16+oo], ev = el[w*16+oo];
    float4 r;
    r.x = fmaxf(fmaf(a2v, acc[oo].x, ev), 0.f);
    r.y = fmaxf(fmaf(a2v, acc[oo].y, ev), 0.f);
    r.z = fmaxf(fmaf(a2v, acc[oo].z, ev), 0.f);
    r.w = fmaxf(fmaf(a2v, acc[oo].w, ev), 0.f);
    *(float4*)(out + (b*TC + w*16 + oo)*TL + l) = r;
  }
}

extern "C" void kernel_launch(void* const* d_in, const int* in_sizes, int n_in,
                              void* d_out, int out_size, void* d_ws, size_t ws_size,
                              hipStream_t stream){
  const float* x  = (const float*)d_in[0];
  const float* wk = (const float*)d_in[1];
  const float* wq = (const float*)d_in[2];
  const float* wv = (const float*)d_in[3];
  const float* wc = (const float*)d_in[4];
  const float* g1 = (const float*)d_in[5];
  /* b1 (d_in[6]) provably cancels through BN2 mean-subtraction */
  const float* wl = (const float*)d_in[7];
  const float* g2 = (const float*)d_in[8];
  const float* b2 = (const float*)d_in[9];
  float* out = (float*)d_out;
  float* ws  = (float*)d_ws;

  k1_gram    <<<dim3(64,16), 256, 0, stream>>>(x, ws);
  kA         <<<dim3(16,16), 256, 0, stream>>>(wq, ws);
  kb12       <<<dim3(16,16), 256, 0, stream>>>(wk, wv, ws);
  kc_mpart   <<<dim3(16,16), 256, 0, stream>>>(wc, ws);
  kd_stats1  <<<dim3(16,16), 256, 0, stream>>>(ws);
  ke_n_stats2<<<dim3(16,16), 256, 0, stream>>>(wl, g1, ws);
  k3_out     <<<dim3(32,16), 256, 0, stream>>>(x, g2, b2, ws, out);
}